// Round 9
// baseline (388.107 us; speedup 1.0000x reference)
//
#include <hip/hip_runtime.h>
#include <math.h>

#define B_   16
#define S_   1056
#define SP_  1088             // k padded to 34*32
#define DM_  256
#define H_   8
#define DK_  32
#define TXT_ 32
#define VID_ 1024
#define SS_  (S_*S_)          // 1115136
#define NQT_ 66               // q-tiles of 16 rows

#define LOG2_10000f 13.28771237954945f
#define LOG2_GAMMAf (-0.15200309344504995f)   // log2(0.9)
#define RSQRT_DKf   0.17677669529663687f      // 1/sqrt(32)
#define TWO_PIf     6.283185307179586f

typedef __attribute__((ext_vector_type(8))) short bf16x8;
typedef __attribute__((ext_vector_type(4))) short bf16x4;
typedef __attribute__((ext_vector_type(4))) float f32x4;

__device__ __forceinline__ short f2bf(float f){
    unsigned u = __float_as_uint(f);
    unsigned r = u + 0x7FFFu + ((u >> 16) & 1u);   // RNE
    return (short)(r >> 16);
}
__device__ __forceinline__ float bf2f(unsigned short s){
    return __uint_as_float(((unsigned)s) << 16);
}

// K=16 bf16 MFMA: A-frag = lane(lr,lg) holds A[row=lr][k=4lg+j] — exactly the
// D-layout of our QK^T tile, so P feeds PV in-lane with zero data movement.
__device__ __forceinline__ f32x4 mfma16(bf16x4 a, bf16x4 b, f32x4 c){
#if __has_builtin(__builtin_amdgcn_mfma_f32_16x16x16bf16_1k)
    return __builtin_amdgcn_mfma_f32_16x16x16bf16_1k(a, b, c, 0, 0, 0);
#else
    f32x4 d = c;
    asm volatile("v_mfma_f32_16x16x16_bf16 %0, %1, %2, %0" : "+v"(d) : "v"(a), "v"(b));
    return d;
#endif
}

// ---------------- mask (bf16) + loss partials ----------------
__global__ __launch_bounds__(256) void k_mask(const float* __restrict__ lvr,
                       const int* __restrict__ row_idx, const int* __restrict__ col_idx,
                       short* __restrict__ maskb, float* __restrict__ partials)
{
    int idx = blockIdx.x*256 + threadIdx.x;
    unsigned ui = (unsigned)idx;
    int i = ui / S_;
    int j = (int)(ui - (unsigned)i*S_);
    float vr, lm;
    if (i == j) { vr = 0.f; lm = 1.f; }
    else {
        float t = lvr[(size_t)row_idx[idx]*VID_ + col_idx[idx]];
        float sg = 1.f/(1.f + expf(-t));
        vr = sg; lm = sg;
    }
    float dmat = (i >= j) ? exp2f((float)(i-j)*LOG2_GAMMAf) : 0.f;
    maskb[idx] = f2bf(dmat * lm);
    float s = vr;
    #pragma unroll
    for (int m=1; m<64; m<<=1) s += __shfl_xor(s, m, 64);
    __shared__ float ws4[4];
    if ((threadIdx.x & 63) == 0) ws4[threadIdx.x>>6] = s;
    __syncthreads();
    if (threadIdx.x == 0) partials[blockIdx.x] = ws4[0]+ws4[1]+ws4[2]+ws4[3];
}

__global__ __launch_bounds__(256) void k_loss(const float* __restrict__ partials,
                                              float* __restrict__ out_loss)
{
    float s = 0.f;
    for (int i = threadIdx.x; i < SS_/256; i += 256) s += partials[i];
    #pragma unroll
    for (int m=1; m<64; m<<=1) s += __shfl_xor(s, m, 64);
    __shared__ float ws4[4];
    if ((threadIdx.x & 63) == 0) ws4[threadIdx.x>>6] = s;
    __syncthreads();
    if (threadIdx.x == 0) out_loss[0] = (ws4[0]+ws4[1]+ws4[2]+ws4[3]) * (1.f/(float)SS_);
}

// ---------------- weight prep ----------------
__global__ __launch_bounds__(256) void k_wprep(
    const float* __restrict__ Wtq, const float* __restrict__ Wtk, const float* __restrict__ Wtv,
    const float* __restrict__ Wvq, const float* __restrict__ Wvk, const float* __restrict__ Wvv,
    const float* __restrict__ Wout, short* __restrict__ WTall, short* __restrict__ WoB)
{
    int seg = blockIdx.x >> 8;
    int r   = blockIdx.x & 255;
    int tid = threadIdx.x;
    if (seg == 6) {
        WoB[r*256 + tid] = f2bf(Wout[r*256 + tid]);
    } else {
        const float* Wsrc = seg==0?Wtq: seg==1?Wtk: seg==2?Wtv: seg==3?Wvq: seg==4?Wvk: Wvv;
        WTall[(size_t)seg*65536 + r*256 + tid] = f2bf(Wsrc[tid*256 + r]);
    }
}

// ---------------- QKV projection via MFMA (unchanged, passing) ----------------
__global__ __launch_bounds__(256, 2) void k_qkv(const float* __restrict__ src,
    const short* __restrict__ WTq, const short* __restrict__ WTk, const short* __restrict__ WTv,
    short* __restrict__ Qb, short* __restrict__ Kb, short* __restrict__ VT, int is_txt)
{
    __shared__ __align__(16) short xb[3][16][256];   // 24 KB
    __shared__ float invf[128];
    __shared__ float lbs[128];
    int tid = threadIdx.x;
    int r0 = blockIdx.x * 16;
    int b, srow0;
    if (is_txt) { b = r0 >> 5;  srow0 = r0 & 31; }
    else        { b = r0 >> 10; srow0 = TXT_ + (r0 & 1023); }

    if (tid < 128) {
        float fk = (float)tid;
        invf[tid] = exp2f(-fk*(1.f/128.f)*LOG2_10000f);
        lbs[tid]  = log2f((2.f*fk + 102.4f) * (1.f/358.4f));
    }
    __syncthreads();

    #pragma unroll
    for (int it = 0; it < 8; ++it) {
        int task = it*256 + tid;
        int k  = task >> 4;
        int rr = task & 15;
        int srow = srow0 + rr;
        float2 x01 = ((const float2*)(src + ((size_t)b*S_ + srow)*DM_))[k];
        float a0, a1, c0, c1;
        if (is_txt) {
            float xe  = (float)(srow + 1) * (TWO_PIf/(32.f + 1e-6f));
            float arg = xe * invf[k];
            float sn = __sinf(arg), cs = __cosf(arg);
            a0 = x01.x + sn; a1 = x01.y + cs;
            c0 = a0; c1 = a1;
        } else {
            int l = srow - TXT_;
            float arg = (float)l * invf[k];
            float sn = __sinf(arg), cs = __cosf(arg);
            float scale = exp2f((float)l*(1.f/512.f)*lbs[k]);
            float rsc = 1.f/scale;
            float y0 = x01.x*cs - x01.y*sn;
            float y1 = x01.y*cs + x01.x*sn;
            a0 = y0*scale; a1 = y1*scale;
            c0 = y0*rsc;   c1 = y1*rsc;
        }
        int col = (2*k) ^ ((rr&7)<<3);
        *(short2*)&xb[0][rr][col] = make_short2(f2bf(a0), f2bf(a1));
        *(short2*)&xb[1][rr][col] = make_short2(f2bf(c0), f2bf(c1));
        *(short2*)&xb[2][rr][col] = make_short2(f2bf(x01.x), f2bf(x01.y));
    }
    __syncthreads();

    int lane = tid & 63;
    int w    = tid >> 6;
    int lr   = lane & 15;
    int lg   = lane >> 4;
    int swzl = (lr & 7) << 3;

    const short* WTs[3] = {WTq, WTk, WTv};
    #pragma unroll
    for (int m = 0; m < 3; ++m) {
        bf16x8 xf[8];
        #pragma unroll
        for (int kk = 0; kk < 8; ++kk)
            xf[kk] = *(const bf16x8*)&xb[m][lr][(kk*32 + lg*8) ^ swzl];
        #pragma unroll
        for (int ct = 0; ct < 4; ++ct) {
            int tb = (w + ct*4) * 16;
            const short* Wp = WTs[m] + (size_t)(tb+lr)*DM_ + lg*8;
            f32x4 acc = {0.f,0.f,0.f,0.f};
            if (m < 2) {
                #pragma unroll
                for (int kk = 0; kk < 8; ++kk) {
                    bf16x8 wf = *(const bf16x8*)(Wp + kk*32);
                    acc = __builtin_amdgcn_mfma_f32_16x16x32_bf16(wf, xf[kk], acc, 0, 0, 0);
                }
                int h  = tb >> 5;
                int d0 = (tb & 31) + lg*4;
                size_t off = ((size_t)(b*H_+h)*S_ + srow0+lr)*DK_ + d0;
                short4 s4;
                if (m == 0) {
                    s4.x=f2bf(acc[0]*RSQRT_DKf); s4.y=f2bf(acc[1]*RSQRT_DKf);
                    s4.z=f2bf(acc[2]*RSQRT_DKf); s4.w=f2bf(acc[3]*RSQRT_DKf);
                    *(short4*)&Qb[off] = s4;
                } else {
                    s4.x=f2bf(acc[0]); s4.y=f2bf(acc[1]);
                    s4.z=f2bf(acc[2]); s4.w=f2bf(acc[3]);
                    *(short4*)&Kb[off] = s4;
                }
            } else {
                #pragma unroll
                for (int kk = 0; kk < 8; ++kk) {
                    bf16x8 wf = *(const bf16x8*)(Wp + kk*32);
                    acc = __builtin_amdgcn_mfma_f32_16x16x32_bf16(xf[kk], wf, acc, 0, 0, 0);
                }
                int o = tb + lr;
                int h = o >> 5, d = o & 31;
                short4 s4;
                s4.x=f2bf(acc[0]); s4.y=f2bf(acc[1]);
                s4.z=f2bf(acc[2]); s4.w=f2bf(acc[3]);
                *(short4*)&VT[((size_t)(b*H_+h)*DK_ + d)*SP_ + srow0 + lg*4] = s4;
            }
        }
    }
}

// ---------------- kernel A: denominators + ctx — in-lane PV, NO LDS ----------------
// Block = 512 thr = 8 waves; wave = head. Grid b-outer (L2: K/V per b stays hot).
// Per 32-k chunk: 2x QK mfma(K=32) -> exp -> bf16x4 (in-lane!) -> 4x PV mfma(K=16).
// Prefetch: peeled rotation, loads unconditional with real consumers (unsinkable).
#define CTX_TILE(KF, MV, VA, VB, PV0, PV1)                                        \
    {                                                                             \
        f32x4 acc = {0.f,0.f,0.f,0.f};                                            \
        acc = __builtin_amdgcn_mfma_f32_16x16x32_bf16(KF, qfrag, acc, 0, 0, 0);   \
        float e0 = __expf(acc[0]*bf2f(MV.x));                                     \
        float e1 = __expf(acc[1]*bf2f(MV.y));                                     \
        float e2 = __expf(acc[2]*bf2f(MV.z));                                     \
        float e3 = __expf(acc[3]*bf2f(MV.w));                                     \
        rssum += (e0+e1) + (e2+e3);                                               \
        bf16x4 pb; pb[0]=f2bf(e0); pb[1]=f2bf(e1); pb[2]=f2bf(e2); pb[3]=f2bf(e3);\
        PV0 = mfma16(pb, VA, PV0);                                                \
        PV1 = mfma16(pb, VB, PV1);                                                \
    }

__global__ __launch_bounds__(512, 4) void k_ctx(const short* __restrict__ Qb,
    const short* __restrict__ Kb, const short* __restrict__ VT,
    const short* __restrict__ maskb, short* __restrict__ ctxb, float* __restrict__ denomG)
{
    int tid  = threadIdx.x;
    int lane = tid & 63;
    int w    = tid >> 6;          // wave = head
    int b    = blockIdx.x / NQT_; // b-outer: consecutive blocks share K/V in L2
    int qt   = blockIdx.x - b*NQT_;
    int q0   = qt * 16;
    int lr   = lane & 15;
    int lg   = lane >> 4;

    const int bh = b*H_ + w;
    bf16x8 qfrag = *(const bf16x8*)(Qb + ((size_t)bh*S_ + q0 + lr)*DK_ + lg*8);
    const short* Kp  = Kb + (size_t)bh*S_*DK_ + (size_t)lr*DK_ + lg*8;    // + k*DK_
    const short* Vp0 = VT + ((size_t)bh*DK_ + lr)*SP_ + 4*lg;             // d = lr
    const short* Vp1 = VT + ((size_t)bh*DK_ + 16 + lr)*SP_ + 4*lg;        // d = lr+16
    const short* Mp  = maskb + (size_t)(q0+lr)*S_ + 4*lg;

    // current-chunk registers (chunk 0)
    bf16x8 k0 = *(const bf16x8*)(Kp);
    bf16x8 k1 = *(const bf16x8*)(Kp + (size_t)16*DK_);
    ushort4 m0 = *(const ushort4*)(Mp);
    ushort4 m1 = *(const ushort4*)(Mp + 16);
    short4 v00 = *(const short4*)(Vp0);          // tile0, d-half0
    short4 v01 = *(const short4*)(Vp1);          // tile0, d-half1
    short4 v10 = *(const short4*)(Vp0 + 16);     // tile1, d-half0
    short4 v11 = *(const short4*)(Vp1 + 16);     // tile1, d-half1

    float rssum = 0.f;
    f32x4 pvA0 = {0.f,0.f,0.f,0.f}, pvA1 = {0.f,0.f,0.f,0.f};
    f32x4 pvB0 = {0.f,0.f,0.f,0.f}, pvB1 = {0.f,0.f,0.f,0.f};

    for (int u = 0; u < 32; ++u) {
        int kn = u*32 + 32;       // <= 1024: always in-bounds, always consumed
        bf16x8 nk0 = *(const bf16x8*)(Kp + (size_t)kn*DK_);
        bf16x8 nk1 = *(const bf16x8*)(Kp + (size_t)(kn+16)*DK_);
        ushort4 nm0 = *(const ushort4*)(Mp + kn);
        ushort4 nm1 = *(const ushort4*)(Mp + kn + 16);
        short4 nv00 = *(const short4*)(Vp0 + kn);
        short4 nv01 = *(const short4*)(Vp1 + kn);
        short4 nv10 = *(const short4*)(Vp0 + kn + 16);
        short4 nv11 = *(const short4*)(Vp1 + kn + 16);

        CTX_TILE(k0, m0, *(const bf16x4*)&v00, *(const bf16x4*)&v01, pvA0, pvA1)
        CTX_TILE(k1, m1, *(const bf16x4*)&v10, *(const bf16x4*)&v11, pvB0, pvB1)

        k0 = nk0; k1 = nk1; m0 = nm0; m1 = nm1;
        v00 = nv00; v01 = nv01; v10 = nv10; v11 = nv11;
    }
    // peeled last chunk (u = 32, k = 1024..1055)
    CTX_TILE(k0, m0, *(const bf16x4*)&v00, *(const bf16x4*)&v01, pvA0, pvA1)
    CTX_TILE(k1, m1, *(const bf16x4*)&v10, *(const bf16x4*)&v11, pvB0, pvB1)

    f32x4 pv0, pv1;
    pv0[0]=pvA0[0]+pvB0[0]; pv0[1]=pvA0[1]+pvB0[1]; pv0[2]=pvA0[2]+pvB0[2]; pv0[3]=pvA0[3]+pvB0[3];
    pv1[0]=pvA1[0]+pvB1[0]; pv1[1]=pvA1[1]+pvB1[1]; pv1[2]=pvA1[2]+pvB1[2]; pv1[3]=pvA1[3]+pvB1[3];

    // row sums: lane (lr,lg) holds partial for q=lr; reduce over lg
    rssum += __shfl_xor(rssum, 16, 64);
    rssum += __shfl_xor(rssum, 32, 64);
    float rd = 1.f / rssum;
    if (lane < 16)
        denomG[(size_t)bh*S_ + q0 + lane] = rd;

    // pv[r] = ctx[q=4lg+r][d=lr (pv0) / lr+16 (pv1)]
    #pragma unroll
    for (int r = 0; r < 4; ++r) {
        float rdq = __shfl(rd, 4*lg + r, 64);
        size_t off = ((size_t)b*S_ + q0 + 4*lg + r)*DM_ + w*DK_ + lr;
        ctxb[off]      = f2bf(pv0[r] * rdq);
        ctxb[off + 16] = f2bf(pv1[r] * rdq);
    }
}

// ---------------- kernel B: att by score recompute (b-outer grid, split loads) ----------------
__global__ __launch_bounds__(256, 4) void k_att(const short* __restrict__ Qb,
    const short* __restrict__ Kb, const short* __restrict__ maskb,
    const float* __restrict__ denomG, float* __restrict__ att)
{
    __shared__ float rd_l[8][16];
    int tid  = threadIdx.x;
    int lane = tid & 63;
    int w    = tid >> 6;
    int b    = blockIdx.x / NQT_;
    int qt   = blockIdx.x - b*NQT_;
    int q0   = qt * 16;

    if (tid < 128)
        rd_l[tid>>4][tid&15] = denomG[(size_t)(b*H_+(tid>>4))*S_ + q0 + (tid&15)] * 0.125f;
    __syncthreads();

    int lr = lane & 15;
    int lg = lane >> 4;

    bf16x8 qf[8];
    #pragma unroll
    for (int h = 0; h < 8; ++h)
        qf[h] = *(const bf16x8*)(Qb + ((size_t)(b*H_+h)*S_ + q0+lr)*DK_ + lg*8);

    const size_t kstride = (size_t)S_*DK_;
    const short* Kbase = Kb + (size_t)b*H_*kstride + lg*8;

    int nt = (w < 2) ? 17 : 16;
    for (int t = 0; t < nt; ++t) {
        int k0 = t*64 + w*16;
        // load phase (8 K-frags + 4 mask rows), then compute phase
        bf16x8 kf[8];
        #pragma unroll
        for (int h = 0; h < 8; ++h)
            kf[h] = *(const bf16x8*)(Kbase + (size_t)h*kstride + (size_t)(k0+lr)*DK_);
        float m0 = bf2f((unsigned short)maskb[(size_t)(q0+4*lg+0)*S_ + k0+lr]);
        float m1 = bf2f((unsigned short)maskb[(size_t)(q0+4*lg+1)*S_ + k0+lr]);
        float m2 = bf2f((unsigned short)maskb[(size_t)(q0+4*lg+2)*S_ + k0+lr]);
        float m3 = bf2f((unsigned short)maskb[(size_t)(q0+4*lg+3)*S_ + k0+lr]);
        f32x4 a = {0.f,0.f,0.f,0.f};
        #pragma unroll
        for (int h = 0; h < 8; ++h) {
            f32x4 s = {0.f,0.f,0.f,0.f};
            s = __builtin_amdgcn_mfma_f32_16x16x32_bf16(qf[h], kf[h], s, 0, 0, 0);
            a[0] = fmaf(__expf(s[0]*m0), rd_l[h][4*lg+0], a[0]);
            a[1] = fmaf(__expf(s[1]*m1), rd_l[h][4*lg+1], a[1]);
            a[2] = fmaf(__expf(s[2]*m2), rd_l[h][4*lg+2], a[2]);
            a[3] = fmaf(__expf(s[3]*m3), rd_l[h][4*lg+3], a[3]);
        }
        att[((size_t)b*S_ + q0+4*lg+0)*S_ + k0+lr] = a[0];
        att[((size_t)b*S_ + q0+4*lg+1)*S_ + k0+lr] = a[1];
        att[((size_t)b*S_ + q0+4*lg+2)*S_ + k0+lr] = a[2];
        att[((size_t)b*S_ + q0+4*lg+3)*S_ + k0+lr] = a[3];
    }
}

// ---------------- out projection via MFMA (no LDS) ----------------
__global__ __launch_bounds__(256, 2) void k_outproj(const short* __restrict__ ctxb,
    const short* __restrict__ WoB, const float* __restrict__ bias, float* __restrict__ out)
{
    int tid  = threadIdx.x;
    int lane = tid & 63;
    int w    = tid >> 6;
    int lr   = lane & 15;
    int lg   = lane >> 4;
    int r0   = blockIdx.x * 16;

    bf16x8 cf[8];
    #pragma unroll
    for (int kk = 0; kk < 8; ++kk)
        cf[kk] = *(const bf16x8*)(ctxb + (size_t)(r0+lr)*DM_ + kk*32 + lg*8);

    #pragma unroll
    for (int ct = 0; ct < 4; ++ct) {
        int tb = (w + ct*4) * 16;
        const short* Wp = WoB + (size_t)(tb+lr)*DM_ + lg*8;
        f32x4 acc = {0.f,0.f,0.f,0.f};
        #pragma unroll
        for (int kk = 0; kk < 8; ++kk) {
            bf16x8 wf = *(const bf16x8*)(Wp + kk*32);
            acc = __builtin_amdgcn_mfma_f32_16x16x32_bf16(wf, cf[kk], acc, 0, 0, 0);
        }
        float4 b4 = *(const float4*)&bias[tb + lg*4];
        float4 o4 = make_float4(acc[0]+b4.x, acc[1]+b4.y, acc[2]+b4.z, acc[3]+b4.w);
        *(float4*)&out[(size_t)(r0+lr)*DM_ + tb + lg*4] = o4;
    }
}

extern "C" void kernel_launch(void* const* d_in, const int* in_sizes, int n_in,
                              void* d_out, int out_size, void* d_ws, size_t ws_size,
                              hipStream_t stream)
{
    (void)in_sizes; (void)n_in; (void)out_size; (void)ws_size;
    const float* src  = (const float*)d_in[0];
    const float* Wtq  = (const float*)d_in[1];
    const float* Wtk  = (const float*)d_in[2];
    const float* Wtv  = (const float*)d_in[3];
    const float* Wvq  = (const float*)d_in[4];
    const float* Wvk  = (const float*)d_in[5];
    const float* Wvv  = (const float*)d_in[6];
    const float* lvr  = (const float*)d_in[7];
    const float* Wout = (const float*)d_in[8];
    const float* bout = (const float*)d_in[9];
    const int*   rid  = (const int*)d_in[10];
    const int*   cid  = (const int*)d_in[11];

    const size_t QKV_SH = (size_t)B_*H_*S_*DK_;    // shorts per Q/K buffer
    const size_t VT_SH  = (size_t)B_*H_*DK_*SP_;   // shorts for V^T
    const size_t CTX_SH = (size_t)B_*S_*DM_;

    float* ws       = (float*)d_ws;
    float* partials = ws;                           // 4356
    float* denomG   = partials + 4356;              // B*H*S
    short* maskb    = (short*)(denomG + (size_t)B_*H_*S_);
    short* Qb       = maskb + SS_;
    short* Kb       = Qb + QKV_SH;
    short* VT       = Kb + QKV_SH;
    short* ctxb     = VT + VT_SH;
    short* WTall    = ctxb + CTX_SH;                // 6*65536
    short* WoB      = WTall + 6*65536;

    float* out  = (float*)d_out;
    float* att  = out + (size_t)B_*S_*DM_;
    float* loss = att + (size_t)B_*S_*S_;

    k_mask<<<SS_/256, 256, 0, stream>>>(lvr, rid, cid, maskb, partials);
    k_wprep<<<7*256, 256, 0, stream>>>(Wtq, Wtk, Wtv, Wvq, Wvk, Wvv, Wout, WTall, WoB);
    k_qkv<<<(B_*TXT_)/16, 256, 0, stream>>>(src, WTall, WTall+65536, WTall+2*65536,
                                            Qb, Kb, VT, 1);
    k_qkv<<<(B_*VID_)/16, 256, 0, stream>>>(src, WTall+3*65536, WTall+4*65536, WTall+5*65536,
                                            Qb, Kb, VT, 0);
    k_ctx<<<B_*NQT_, 512, 0, stream>>>(Qb, Kb, VT, maskb, ctxb, denomG);
    k_att<<<B_*NQT_, 256, 0, stream>>>(Qb, Kb, maskb, denomG, att);
    k_outproj<<<(B_*S_)/16, 256, 0, stream>>>(ctxb, WoB, bout, out);
    k_loss<<<1, 256, 0, stream>>>(partials, loss);
}

// Round 10
// 324.857 us; speedup vs baseline: 1.1947x; 1.1947x over previous
//
#include <hip/hip_runtime.h>
#include <math.h>

#define B_   16
#define S_   1056
#define SP_  1088             // k padded to 34*32
#define DM_  256
#define H_   8
#define DK_  32
#define TXT_ 32
#define VID_ 1024
#define SS_  (S_*S_)          // 1115136
#define NQT_ 66               // q-tiles of 16 rows (k_att)
#define NQT32_ 33             // q-tiles of 32 rows (k_ctx)

#define LOG2_10000f 13.28771237954945f
#define LOG2_GAMMAf (-0.15200309344504995f)   // log2(0.9)
#define RSQRT_DKf   0.17677669529663687f      // 1/sqrt(32)
#define TWO_PIf     6.283185307179586f

typedef __attribute__((ext_vector_type(8))) short bf16x8;
typedef __attribute__((ext_vector_type(4))) short bf16x4;
typedef __attribute__((ext_vector_type(4))) float f32x4;

__device__ __forceinline__ short f2bf(float f){
    unsigned u = __float_as_uint(f);
    unsigned r = u + 0x7FFFu + ((u >> 16) & 1u);   // RNE
    return (short)(r >> 16);
}
__device__ __forceinline__ float bf2f(unsigned short s){
    return __uint_as_float(((unsigned)s) << 16);
}

// K=16 bf16 MFMA: A-frag lane(lr,lg) holds A[row=lr][k=4lg+j] — exactly the
// D-layout of the QK^T tile (P[q=lr][k=4lg+r]), so P feeds PV in-lane.
__device__ __forceinline__ f32x4 mfma16(bf16x4 a, bf16x4 b, f32x4 c){
#if __has_builtin(__builtin_amdgcn_mfma_f32_16x16x16bf16_1k)
    return __builtin_amdgcn_mfma_f32_16x16x16bf16_1k(a, b, c, 0, 0, 0);
#else
    f32x4 d = c;
    asm volatile("v_mfma_f32_16x16x16_bf16 %0, %1, %2, %0" : "+v"(d) : "v"(a), "v"(b));
    return d;
#endif
}

// ---------------- mask (bf16) + loss partials ----------------
__global__ __launch_bounds__(256) void k_mask(const float* __restrict__ lvr,
                       const int* __restrict__ row_idx, const int* __restrict__ col_idx,
                       short* __restrict__ maskb, float* __restrict__ partials)
{
    int idx = blockIdx.x*256 + threadIdx.x;
    unsigned ui = (unsigned)idx;
    int i = ui / S_;
    int j = (int)(ui - (unsigned)i*S_);
    float vr, lm;
    if (i == j) { vr = 0.f; lm = 1.f; }
    else {
        float t = lvr[(size_t)row_idx[idx]*VID_ + col_idx[idx]];
        float sg = 1.f/(1.f + expf(-t));
        vr = sg; lm = sg;
    }
    float dmat = (i >= j) ? exp2f((float)(i-j)*LOG2_GAMMAf) : 0.f;
    maskb[idx] = f2bf(dmat * lm);
    float s = vr;
    #pragma unroll
    for (int m=1; m<64; m<<=1) s += __shfl_xor(s, m, 64);
    __shared__ float ws4[4];
    if ((threadIdx.x & 63) == 0) ws4[threadIdx.x>>6] = s;
    __syncthreads();
    if (threadIdx.x == 0) partials[blockIdx.x] = ws4[0]+ws4[1]+ws4[2]+ws4[3];
}

__global__ __launch_bounds__(256) void k_loss(const float* __restrict__ partials,
                                              float* __restrict__ out_loss)
{
    float s = 0.f;
    for (int i = threadIdx.x; i < SS_/256; i += 256) s += partials[i];
    #pragma unroll
    for (int m=1; m<64; m<<=1) s += __shfl_xor(s, m, 64);
    __shared__ float ws4[4];
    if ((threadIdx.x & 63) == 0) ws4[threadIdx.x>>6] = s;
    __syncthreads();
    if (threadIdx.x == 0) out_loss[0] = (ws4[0]+ws4[1]+ws4[2]+ws4[3]) * (1.f/(float)SS_);
}

// ---------------- weight prep ----------------
__global__ __launch_bounds__(256) void k_wprep(
    const float* __restrict__ Wtq, const float* __restrict__ Wtk, const float* __restrict__ Wtv,
    const float* __restrict__ Wvq, const float* __restrict__ Wvk, const float* __restrict__ Wvv,
    const float* __restrict__ Wout, short* __restrict__ WTall, short* __restrict__ WoB)
{
    int seg = blockIdx.x >> 8;
    int r   = blockIdx.x & 255;
    int tid = threadIdx.x;
    if (seg == 6) {
        WoB[r*256 + tid] = f2bf(Wout[r*256 + tid]);
    } else {
        const float* Wsrc = seg==0?Wtq: seg==1?Wtk: seg==2?Wtv: seg==3?Wvq: seg==4?Wvk: Wvv;
        WTall[(size_t)seg*65536 + r*256 + tid] = f2bf(Wsrc[tid*256 + r]);
    }
}

// ---------------- QKV projection via MFMA (unchanged, passing) ----------------
__global__ __launch_bounds__(256, 2) void k_qkv(const float* __restrict__ src,
    const short* __restrict__ WTq, const short* __restrict__ WTk, const short* __restrict__ WTv,
    short* __restrict__ Qb, short* __restrict__ Kb, short* __restrict__ VT, int is_txt)
{
    __shared__ __align__(16) short xb[3][16][256];   // 24 KB
    __shared__ float invf[128];
    __shared__ float lbs[128];
    int tid = threadIdx.x;
    int r0 = blockIdx.x * 16;
    int b, srow0;
    if (is_txt) { b = r0 >> 5;  srow0 = r0 & 31; }
    else        { b = r0 >> 10; srow0 = TXT_ + (r0 & 1023); }

    if (tid < 128) {
        float fk = (float)tid;
        invf[tid] = exp2f(-fk*(1.f/128.f)*LOG2_10000f);
        lbs[tid]  = log2f((2.f*fk + 102.4f) * (1.f/358.4f));
    }
    __syncthreads();

    #pragma unroll
    for (int it = 0; it < 8; ++it) {
        int task = it*256 + tid;
        int k  = task >> 4;
        int rr = task & 15;
        int srow = srow0 + rr;
        float2 x01 = ((const float2*)(src + ((size_t)b*S_ + srow)*DM_))[k];
        float a0, a1, c0, c1;
        if (is_txt) {
            float xe  = (float)(srow + 1) * (TWO_PIf/(32.f + 1e-6f));
            float arg = xe * invf[k];
            float sn = __sinf(arg), cs = __cosf(arg);
            a0 = x01.x + sn; a1 = x01.y + cs;
            c0 = a0; c1 = a1;
        } else {
            int l = srow - TXT_;
            float arg = (float)l * invf[k];
            float sn = __sinf(arg), cs = __cosf(arg);
            float scale = exp2f((float)l*(1.f/512.f)*lbs[k]);
            float rsc = 1.f/scale;
            float y0 = x01.x*cs - x01.y*sn;
            float y1 = x01.y*cs + x01.x*sn;
            a0 = y0*scale; a1 = y1*scale;
            c0 = y0*rsc;   c1 = y1*rsc;
        }
        int col = (2*k) ^ ((rr&7)<<3);
        *(short2*)&xb[0][rr][col] = make_short2(f2bf(a0), f2bf(a1));
        *(short2*)&xb[1][rr][col] = make_short2(f2bf(c0), f2bf(c1));
        *(short2*)&xb[2][rr][col] = make_short2(f2bf(x01.x), f2bf(x01.y));
    }
    __syncthreads();

    int lane = tid & 63;
    int w    = tid >> 6;
    int lr   = lane & 15;
    int lg   = lane >> 4;
    int swzl = (lr & 7) << 3;

    const short* WTs[3] = {WTq, WTk, WTv};
    #pragma unroll
    for (int m = 0; m < 3; ++m) {
        bf16x8 xf[8];
        #pragma unroll
        for (int kk = 0; kk < 8; ++kk)
            xf[kk] = *(const bf16x8*)&xb[m][lr][(kk*32 + lg*8) ^ swzl];
        #pragma unroll
        for (int ct = 0; ct < 4; ++ct) {
            int tb = (w + ct*4) * 16;
            const short* Wp = WTs[m] + (size_t)(tb+lr)*DM_ + lg*8;
            f32x4 acc = {0.f,0.f,0.f,0.f};
            if (m < 2) {
                #pragma unroll
                for (int kk = 0; kk < 8; ++kk) {
                    bf16x8 wf = *(const bf16x8*)(Wp + kk*32);
                    acc = __builtin_amdgcn_mfma_f32_16x16x32_bf16(wf, xf[kk], acc, 0, 0, 0);
                }
                int h  = tb >> 5;
                int d0 = (tb & 31) + lg*4;
                size_t off = ((size_t)(b*H_+h)*S_ + srow0+lr)*DK_ + d0;
                short4 s4;
                if (m == 0) {
                    s4.x=f2bf(acc[0]*RSQRT_DKf); s4.y=f2bf(acc[1]*RSQRT_DKf);
                    s4.z=f2bf(acc[2]*RSQRT_DKf); s4.w=f2bf(acc[3]*RSQRT_DKf);
                    *(short4*)&Qb[off] = s4;
                } else {
                    s4.x=f2bf(acc[0]); s4.y=f2bf(acc[1]);
                    s4.z=f2bf(acc[2]); s4.w=f2bf(acc[3]);
                    *(short4*)&Kb[off] = s4;
                }
            } else {
                #pragma unroll
                for (int kk = 0; kk < 8; ++kk) {
                    bf16x8 wf = *(const bf16x8*)(Wp + kk*32);
                    acc = __builtin_amdgcn_mfma_f32_16x16x32_bf16(xf[kk], wf, acc, 0, 0, 0);
                }
                int o = tb + lr;
                int h = o >> 5, d = o & 31;
                short4 s4;
                s4.x=f2bf(acc[0]); s4.y=f2bf(acc[1]);
                s4.z=f2bf(acc[2]); s4.w=f2bf(acc[3]);
                *(short4*)&VT[((size_t)(b*H_+h)*DK_ + d)*SP_ + srow0 + lg*4] = s4;
            }
        }
    }
}

// ---------------- kernel A: denominators + ctx — in-lane PV, 32-q tile, b-inner grid ----------------
// Grid qt-major: XCD = blk%8 = b%8 -> each XCD holds K/V for b in {x, x+8} (2.2 MB, L2-resident).
// Block = 512 thr = 8 waves = 8 heads, q-tile 32 (2 Q frags/wave, 4 PV accumulators).
// Per 32-k chunk: 4 QK mfma(K=32) + 16 exp + 8 PV mfma(K=16), 10 loads prefetched 1 chunk ahead.
#define CTX_TILE2(KF, MH0, MH1, VA, VB)                                            \
    {                                                                              \
        f32x4 acc0 = {0.f,0.f,0.f,0.f};                                            \
        acc0 = __builtin_amdgcn_mfma_f32_16x16x32_bf16(KF, qf0, acc0, 0, 0, 0);    \
        f32x4 acc1 = {0.f,0.f,0.f,0.f};                                            \
        acc1 = __builtin_amdgcn_mfma_f32_16x16x32_bf16(KF, qf1, acc1, 0, 0, 0);    \
        float e0 = __expf(acc0[0]*bf2f(MH0.x));                                    \
        float e1 = __expf(acc0[1]*bf2f(MH0.y));                                    \
        float e2 = __expf(acc0[2]*bf2f(MH0.z));                                    \
        float e3 = __expf(acc0[3]*bf2f(MH0.w));                                    \
        rssum0 += (e0+e1) + (e2+e3);                                               \
        bf16x4 pb0; pb0[0]=f2bf(e0); pb0[1]=f2bf(e1); pb0[2]=f2bf(e2); pb0[3]=f2bf(e3); \
        float f0 = __expf(acc1[0]*bf2f(MH1.x));                                    \
        float f1 = __expf(acc1[1]*bf2f(MH1.y));                                    \
        float f2 = __expf(acc1[2]*bf2f(MH1.z));                                    \
        float f3 = __expf(acc1[3]*bf2f(MH1.w));                                    \
        rssum1 += (f0+f1) + (f2+f3);                                               \
        bf16x4 pb1; pb1[0]=f2bf(f0); pb1[1]=f2bf(f1); pb1[2]=f2bf(f2); pb1[3]=f2bf(f3); \
        pv00 = mfma16(pb0, VA, pv00);                                              \
        pv01 = mfma16(pb0, VB, pv01);                                              \
        pv10 = mfma16(pb1, VA, pv10);                                              \
        pv11 = mfma16(pb1, VB, pv11);                                              \
    }

__global__ __launch_bounds__(512, 4) void k_ctx(const short* __restrict__ Qb,
    const short* __restrict__ Kb, const short* __restrict__ VT,
    const short* __restrict__ maskb, short* __restrict__ ctxb, float* __restrict__ denomG)
{
    int tid  = threadIdx.x;
    int lane = tid & 63;
    int w    = tid >> 6;              // wave = head
    int b    = blockIdx.x & 15;       // b-inner: XCD pinning (b%8)
    int qt   = blockIdx.x >> 4;       // 0..32
    int q0   = qt * 32;
    int lr   = lane & 15;
    int lg   = lane >> 4;

    const int bh = b*H_ + w;
    bf16x8 qf0 = *(const bf16x8*)(Qb + ((size_t)bh*S_ + q0 + lr)*DK_ + lg*8);
    bf16x8 qf1 = *(const bf16x8*)(Qb + ((size_t)bh*S_ + q0 + 16 + lr)*DK_ + lg*8);
    const short* Kp  = Kb + (size_t)bh*S_*DK_ + (size_t)lr*DK_ + lg*8;    // + k*DK_
    const short* Vp0 = VT + ((size_t)bh*DK_ + lr)*SP_ + 4*lg;             // d = lr
    const short* Vp1 = VT + ((size_t)bh*DK_ + 16 + lr)*SP_ + 4*lg;        // d = lr+16
    const short* Mp0 = maskb + (size_t)(q0+lr)*S_ + 4*lg;                 // q-half 0
    const short* Mp1 = maskb + (size_t)(q0+16+lr)*S_ + 4*lg;              // q-half 1

    // current-chunk registers (chunk 0; k-tiles at 0 and 16)
    bf16x8 k0 = *(const bf16x8*)(Kp);
    bf16x8 k1 = *(const bf16x8*)(Kp + (size_t)16*DK_);
    ushort4 m00 = *(const ushort4*)(Mp0);          // tile0, q-half0
    ushort4 m01 = *(const ushort4*)(Mp1);          // tile0, q-half1
    ushort4 m10 = *(const ushort4*)(Mp0 + 16);     // tile1, q-half0
    ushort4 m11 = *(const ushort4*)(Mp1 + 16);     // tile1, q-half1
    short4 v00 = *(const short4*)(Vp0);            // tile0, d-half0
    short4 v01 = *(const short4*)(Vp1);            // tile0, d-half1
    short4 v10 = *(const short4*)(Vp0 + 16);       // tile1, d-half0
    short4 v11 = *(const short4*)(Vp1 + 16);       // tile1, d-half1

    float rssum0 = 0.f, rssum1 = 0.f;
    f32x4 pv00 = {0.f,0.f,0.f,0.f}, pv01 = {0.f,0.f,0.f,0.f};
    f32x4 pv10 = {0.f,0.f,0.f,0.f}, pv11 = {0.f,0.f,0.f,0.f};

    for (int u = 0; u < 32; ++u) {
        int kn = u*32 + 32;           // <= 1024: in-bounds, always consumed
        bf16x8 nk0 = *(const bf16x8*)(Kp + (size_t)kn*DK_);
        bf16x8 nk1 = *(const bf16x8*)(Kp + (size_t)(kn+16)*DK_);
        ushort4 nm00 = *(const ushort4*)(Mp0 + kn);
        ushort4 nm01 = *(const ushort4*)(Mp1 + kn);
        ushort4 nm10 = *(const ushort4*)(Mp0 + kn + 16);
        ushort4 nm11 = *(const ushort4*)(Mp1 + kn + 16);
        short4 nv00 = *(const short4*)(Vp0 + kn);
        short4 nv01 = *(const short4*)(Vp1 + kn);
        short4 nv10 = *(const short4*)(Vp0 + kn + 16);
        short4 nv11 = *(const short4*)(Vp1 + kn + 16);

        CTX_TILE2(k0, m00, m01, *(const bf16x4*)&v00, *(const bf16x4*)&v01)
        CTX_TILE2(k1, m10, m11, *(const bf16x4*)&v10, *(const bf16x4*)&v11)

        k0 = nk0; k1 = nk1;
        m00 = nm00; m01 = nm01; m10 = nm10; m11 = nm11;
        v00 = nv00; v01 = nv01; v10 = nv10; v11 = nv11;
    }
    // peeled last chunk (k = 1024..1055)
    CTX_TILE2(k0, m00, m01, *(const bf16x4*)&v00, *(const bf16x4*)&v01)
    CTX_TILE2(k1, m10, m11, *(const bf16x4*)&v10, *(const bf16x4*)&v11)

    // row sums: lane (lr,lg) holds partial for q=lr (+16); reduce over lg
    rssum0 += __shfl_xor(rssum0, 16, 64);
    rssum0 += __shfl_xor(rssum0, 32, 64);
    rssum1 += __shfl_xor(rssum1, 16, 64);
    rssum1 += __shfl_xor(rssum1, 32, 64);
    float rd0 = 1.f / rssum0;
    float rd1 = 1.f / rssum1;
    if (lane < 16) {
        denomG[(size_t)bh*S_ + q0 + lane]      = rd0;
        denomG[(size_t)bh*S_ + q0 + 16 + lane] = rd1;
    }

    // pv[r] = ctx[q = q0 + qh*16 + 4lg + r][d = lr (A) / lr+16 (B)]
    #pragma unroll
    for (int r = 0; r < 4; ++r) {
        float rdq0 = __shfl(rd0, 4*lg + r, 64);
        float rdq1 = __shfl(rd1, 4*lg + r, 64);
        size_t off0 = ((size_t)b*S_ + q0 + 4*lg + r)*DM_ + w*DK_ + lr;
        size_t off1 = ((size_t)b*S_ + q0 + 16 + 4*lg + r)*DM_ + w*DK_ + lr;
        ctxb[off0]      = f2bf(pv00[r] * rdq0);
        ctxb[off0 + 16] = f2bf(pv01[r] * rdq0);
        ctxb[off1]      = f2bf(pv10[r] * rdq1);
        ctxb[off1 + 16] = f2bf(pv11[r] * rdq1);
    }
}

// ---------------- kernel B: att by score recompute (b-inner grid) ----------------
__global__ __launch_bounds__(256, 4) void k_att(const short* __restrict__ Qb,
    const short* __restrict__ Kb, const short* __restrict__ maskb,
    const float* __restrict__ denomG, float* __restrict__ att)
{
    __shared__ float rd_l[8][16];
    int tid  = threadIdx.x;
    int lane = tid & 63;
    int w    = tid >> 6;
    int b    = blockIdx.x & 15;       // b-inner: XCD pinning
    int qt   = blockIdx.x >> 4;
    int q0   = qt * 16;

    if (tid < 128)
        rd_l[tid>>4][tid&15] = denomG[(size_t)(b*H_+(tid>>4))*S_ + q0 + (tid&15)] * 0.125f;
    __syncthreads();

    int lr = lane & 15;
    int lg = lane >> 4;

    bf16x8 qf[8];
    #pragma unroll
    for (int h = 0; h < 8; ++h)
        qf[h] = *(const bf16x8*)(Qb + ((size_t)(b*H_+h)*S_ + q0+lr)*DK_ + lg*8);

    const size_t kstride = (size_t)S_*DK_;
    const short* Kbase = Kb + (size_t)b*H_*kstride + lg*8;

    int nt = (w < 2) ? 17 : 16;
    for (int t = 0; t < nt; ++t) {
        int k0 = t*64 + w*16;
        bf16x8 kf[8];
        #pragma unroll
        for (int h = 0; h < 8; ++h)
            kf[h] = *(const bf16x8*)(Kbase + (size_t)h*kstride + (size_t)(k0+lr)*DK_);
        float m0 = bf2f((unsigned short)maskb[(size_t)(q0+4*lg+0)*S_ + k0+lr]);
        float m1 = bf2f((unsigned short)maskb[(size_t)(q0+4*lg+1)*S_ + k0+lr]);
        float m2 = bf2f((unsigned short)maskb[(size_t)(q0+4*lg+2)*S_ + k0+lr]);
        float m3 = bf2f((unsigned short)maskb[(size_t)(q0+4*lg+3)*S_ + k0+lr]);
        f32x4 a = {0.f,0.f,0.f,0.f};
        #pragma unroll
        for (int h = 0; h < 8; ++h) {
            f32x4 s = {0.f,0.f,0.f,0.f};
            s = __builtin_amdgcn_mfma_f32_16x16x32_bf16(qf[h], kf[h], s, 0, 0, 0);
            a[0] = fmaf(__expf(s[0]*m0), rd_l[h][4*lg+0], a[0]);
            a[1] = fmaf(__expf(s[1]*m1), rd_l[h][4*lg+1], a[1]);
            a[2] = fmaf(__expf(s[2]*m2), rd_l[h][4*lg+2], a[2]);
            a[3] = fmaf(__expf(s[3]*m3), rd_l[h][4*lg+3], a[3]);
        }
        att[((size_t)b*S_ + q0+4*lg+0)*S_ + k0+lr] = a[0];
        att[((size_t)b*S_ + q0+4*lg+1)*S_ + k0+lr] = a[1];
        att[((size_t)b*S_ + q0+4*lg+2)*S_ + k0+lr] = a[2];
        att[((size_t)b*S_ + q0+4*lg+3)*S_ + k0+lr] = a[3];
    }
}

// ---------------- out projection via MFMA (no LDS) ----------------
__global__ __launch_bounds__(256, 2) void k_outproj(const short* __restrict__ ctxb,
    const short* __restrict__ WoB, const float* __restrict__ bias, float* __restrict__ out)
{
    int tid  = threadIdx.x;
    int lane = tid & 63;
    int w    = tid >> 6;
    int lr   = lane & 15;
    int lg   = lane >> 4;
    int r0   = blockIdx.x * 16;

    bf16x8 cf[8];
    #pragma unroll
    for (int kk = 0; kk < 8; ++kk)
        cf[kk] = *(const bf16x8*)(ctxb + (size_t)(r0+lr)*DM_ + kk*32 + lg*8);

    #pragma unroll
    for (int ct = 0; ct < 4; ++ct) {
        int tb = (w + ct*4) * 16;
        const short* Wp = WoB + (size_t)(tb+lr)*DM_ + lg*8;
        f32x4 acc = {0.f,0.f,0.f,0.f};
        #pragma unroll
        for (int kk = 0; kk < 8; ++kk) {
            bf16x8 wf = *(const bf16x8*)(Wp + kk*32);
            acc = __builtin_amdgcn_mfma_f32_16x16x32_bf16(wf, cf[kk], acc, 0, 0, 0);
        }
        float4 b4 = *(const float4*)&bias[tb + lg*4];
        float4 o4 = make_float4(acc[0]+b4.x, acc[1]+b4.y, acc[2]+b4.z, acc[3]+b4.w);
        *(float4*)&out[(size_t)(r0+lr)*DM_ + tb + lg*4] = o4;
    }
}

extern "C" void kernel_launch(void* const* d_in, const int* in_sizes, int n_in,
                              void* d_out, int out_size, void* d_ws, size_t ws_size,
                              hipStream_t stream)
{
    (void)in_sizes; (void)n_in; (void)out_size; (void)ws_size;
    const float* src  = (const float*)d_in[0];
    const float* Wtq  = (const float*)d_in[1];
    const float* Wtk  = (const float*)d_in[2];
    const float* Wtv  = (const float*)d_in[3];
    const float* Wvq  = (const float*)d_in[4];
    const float* Wvk  = (const float*)d_in[5];
    const float* Wvv  = (const float*)d_in[6];
    const float* lvr  = (const float*)d_in[7];
    const float* Wout = (const float*)d_in[8];
    const float* bout = (const float*)d_in[9];
    const int*   rid  = (const int*)d_in[10];
    const int*   cid  = (const int*)d_in[11];

    const size_t QKV_SH = (size_t)B_*H_*S_*DK_;    // shorts per Q/K buffer
    const size_t VT_SH  = (size_t)B_*H_*DK_*SP_;   // shorts for V^T
    const size_t CTX_SH = (size_t)B_*S_*DM_;

    float* ws       = (float*)d_ws;
    float* partials = ws;                           // 4356
    float* denomG   = partials + 4356;              // B*H*S
    short* maskb    = (short*)(denomG + (size_t)B_*H_*S_);
    short* Qb       = maskb + SS_;
    short* Kb       = Qb + QKV_SH;
    short* VT       = Kb + QKV_SH;
    short* ctxb     = VT + VT_SH;
    short* WTall    = ctxb + CTX_SH;                // 6*65536
    short* WoB      = WTall + 6*65536;

    float* out  = (float*)d_out;
    float* att  = out + (size_t)B_*S_*DM_;
    float* loss = att + (size_t)B_*S_*S_;

    k_mask<<<SS_/256, 256, 0, stream>>>(lvr, rid, cid, maskb, partials);
    k_wprep<<<7*256, 256, 0, stream>>>(Wtq, Wtk, Wtv, Wvq, Wvk, Wvv, Wout, WTall, WoB);
    k_qkv<<<(B_*TXT_)/16, 256, 0, stream>>>(src, WTall, WTall+65536, WTall+2*65536,
                                            Qb, Kb, VT, 1);
    k_qkv<<<(B_*VID_)/16, 256, 0, stream>>>(src, WTall+3*65536, WTall+4*65536, WTall+5*65536,
                                            Qb, Kb, VT, 0);
    k_ctx<<<B_*NQT32_, 512, 0, stream>>>(Qb, Kb, VT, maskb, ctxb, denomG);
    k_att<<<B_*NQT_, 256, 0, stream>>>(Qb, Kb, maskb, denomG, att);
    k_outproj<<<(B_*S_)/16, 256, 0, stream>>>(ctxb, WoB, bout, out);
    k_loss<<<1, 256, 0, stream>>>(partials, loss);
}